// Round 2
// baseline (1477.185 us; speedup 1.0000x reference)
//
#include <hip/hip_runtime.h>
#include <hip/hip_bf16.h>
#include <stdint.h>

// Problem constants
#define NN 50000            // nodes
#define RR 33               // relations
#define EE 3200000          // edges
#define DD 1600             // emb dim
#define WSZ 16              // weights_size
#define CC 10               // classes
#define NC (RR*WSZ)         // 528 columns of H / H2
#define NCP 640             // padded to 5 * 128 column tiles

typedef __attribute__((ext_vector_type(8))) short bfrag;   // 8 bf16 = 4 VGPRs
typedef __attribute__((ext_vector_type(4))) float f32x4;

__device__ __forceinline__ unsigned short f2bf(float f) {
  union { float f; unsigned u; } v; v.f = f;
  unsigned r = v.u + 0x7FFF + ((v.u >> 16) & 1);   // RNE, inputs are finite
  return (unsigned short)(r >> 16);
}

// ---------------- 1) emb fp32 -> bf16 (A matrix) ----------------
__global__ __launch_bounds__(256) void k_conv_a(const float4* __restrict__ src,
                                                ushort4* __restrict__ dst) {
  size_t i = (size_t)blockIdx.x * 256 + threadIdx.x;   // exactly 20,000,000 threads
  float4 v = src[i];
  ushort4 o;
  o.x = f2bf(v.x); o.y = f2bf(v.y); o.z = f2bf(v.z); o.w = f2bf(v.w);
  dst[i] = o;
}

// ---------------- 2) build B^T bf16 [NCP][DD], Bt[n][k] = w1[n>>4][k][n&15] ----
__global__ __launch_bounds__(256) void k_build_bt(const float* __restrict__ w1,
                                                  __hip_bfloat16* __restrict__ bt) {
  int idx = blockIdx.x * 256 + threadIdx.x;            // NCP*DD = 1,024,000 exact
  int n = idx / DD, k = idx - n * DD;
  float v = 0.f;
  if (n < NC) {
    int r = n >> 4, o = n & 15;
    v = w1[((size_t)r * DD + k) * WSZ + o];
  }
  unsigned short b = f2bf(v);
  *reinterpret_cast<unsigned short*>(&bt[idx]) = b;
}

// ---------------- 3a) histogram of edge_s ----------------
__global__ __launch_bounds__(256) void k_hist(const int* __restrict__ es,
                                              int* __restrict__ counts) {
  int i = blockIdx.x * 256 + threadIdx.x;              // EE exact
  atomicAdd(&counts[es[i]], 1);
}

// ---------------- 3b) exclusive scan (single block) ----------------
__global__ __launch_bounds__(1024) void k_scan(const int* __restrict__ counts,
                                               int* __restrict__ offs,
                                               int* __restrict__ ptr) {
  __shared__ int part[1024];
  int t = threadIdx.x;
  const int CH = 49;                                   // 49*1024 >= NN
  int base = t * CH;
  int s = 0;
  for (int j = 0; j < CH; ++j) { int i = base + j; if (i < NN) s += counts[i]; }
  part[t] = s;
  __syncthreads();
  for (int off = 1; off < 1024; off <<= 1) {
    int v = (t >= off) ? part[t - off] : 0;
    __syncthreads();
    part[t] += v;
    __syncthreads();
  }
  int running = part[t] - s;                           // exclusive prefix of this chunk
  for (int j = 0; j < CH; ++j) {
    int i = base + j;
    if (i < NN) { offs[i] = running; ptr[i] = running; running += counts[i]; }
  }
  if (t == 0) offs[NN] = part[1023];
}

// ---------------- 3c) scatter edges into CSR order ----------------
__global__ __launch_bounds__(256) void k_scatter(const int* __restrict__ es,
                                                 const int* __restrict__ ep,
                                                 const int* __restrict__ eo,
                                                 const float* __restrict__ ev,
                                                 int* __restrict__ ptr,
                                                 uint2* __restrict__ recs) {
  int i = blockIdx.x * 256 + threadIdx.x;              // EE exact
  int s = es[i];
  int pos = atomicAdd(&ptr[s], 1);
  uint2 r;
  r.x = (unsigned)eo[i] | ((unsigned)ep[i] << 16);     // o < 65536, p < 33
  r.y = __float_as_uint(ev[i]);
  recs[pos] = r;
}

// ---------------- 4) GEMM: H[NN][NC] = A[NN][DD] @ B[DD][NC]  (bf16 MFMA) ------
#define BM 128
#define BN 128
#define BK 32

__global__ __launch_bounds__(256) void k_gemm(const __hip_bfloat16* __restrict__ A,
                                              const __hip_bfloat16* __restrict__ Bt,
                                              float* __restrict__ H) {
  __shared__ __align__(16) __hip_bfloat16 As[BM * BK];   // [row][k]
  __shared__ __align__(16) __hip_bfloat16 Bs[BN * BK];   // [col][k] (Bt layout)
  int tid  = threadIdx.x;
  int wave = tid >> 6, lane = tid & 63;
  int m0 = blockIdx.x * BM;
  int n0 = blockIdx.y * BN;
  int wm = (wave >> 1) * 64, wn = (wave & 1) * 64;       // 2x2 wave quadrants
  int ld = lane & 15, quad = lane >> 4;

  f32x4 acc[4][4] = {};

  for (int k0 = 0; k0 < DD; k0 += BK) {
    __syncthreads();
#pragma unroll
    for (int j = 0; j < 2; ++j) {                        // stage A tile: 512 x 16B
      int idx = j * 256 + tid;
      int row = idx >> 2;
      int kc  = (idx & 3) * 8;
      int grow = m0 + row; if (grow > NN - 1) grow = NN - 1;
      const __hip_bfloat16* gp = A + (size_t)grow * DD + k0 + kc;
      __builtin_amdgcn_global_load_lds(
          (const __attribute__((address_space(1))) void*)gp,
          (__attribute__((address_space(3))) void*)(As + idx * 8), 16, 0, 0);
    }
#pragma unroll
    for (int j = 0; j < 2; ++j) {                        // stage Bt tile: 512 x 16B
      int idx = j * 256 + tid;
      int col = idx >> 2;
      int kc  = (idx & 3) * 8;
      const __hip_bfloat16* gp = Bt + (size_t)(n0 + col) * DD + k0 + kc;
      __builtin_amdgcn_global_load_lds(
          (const __attribute__((address_space(1))) void*)gp,
          (__attribute__((address_space(3))) void*)(Bs + idx * 8), 16, 0, 0);
    }
    __syncthreads();                                     // compiler drains vmcnt here

    bfrag af[4], bf[4];
#pragma unroll
    for (int mi = 0; mi < 4; ++mi)
      af[mi] = *(const bfrag*)(As + (wm + mi * 16 + ld) * BK + quad * 8);
#pragma unroll
    for (int ni = 0; ni < 4; ++ni)
      bf[ni] = *(const bfrag*)(Bs + (wn + ni * 16 + ld) * BK + quad * 8);
#pragma unroll
    for (int mi = 0; mi < 4; ++mi)
#pragma unroll
      for (int ni = 0; ni < 4; ++ni)
        acc[mi][ni] = __builtin_amdgcn_mfma_f32_16x16x32_bf16(af[mi], bf[ni],
                                                              acc[mi][ni], 0, 0, 0);
  }

#pragma unroll
  for (int mi = 0; mi < 4; ++mi)
#pragma unroll
    for (int ni = 0; ni < 4; ++ni) {
      int col = n0 + wn + ni * 16 + ld;
      if (col >= NC) continue;
#pragma unroll
      for (int r = 0; r < 4; ++r) {
        int row = m0 + wm + mi * 16 + quad * 4 + r;      // C/D: col=lane&15, row=quad*4+reg
        if (row < NN) H[(size_t)row * NC + col] = acc[mi][ni][r];
      }
    }
}

// ---------------- 5) layer-1 aggregation: one wave per destination node -------
__global__ __launch_bounds__(256) void k_agg1(const uint2* __restrict__ recs,
                                              const int* __restrict__ offs,
                                              const float* __restrict__ H,
                                              const float* __restrict__ bias1,
                                              float* __restrict__ h1) {
  int wid  = (blockIdx.x * 256 + threadIdx.x) >> 6;      // exactly NN waves
  int lane = threadIdx.x & 63;
  int grp = lane >> 4, c = lane & 15;
  int beg = offs[wid], end = offs[wid + 1];
  float acc = 0.f;
  for (int e = beg + grp; e < end; e += 4) {
    uint2 r = recs[e];                                   // broadcast within group
    int o = r.x & 0xFFFF, p = r.x >> 16;
    float val = __uint_as_float(r.y);
    acc += val * H[(size_t)o * NC + p * WSZ + c];        // 64B-aligned cacheline
  }
  acc += __shfl_xor(acc, 16, 64);
  acc += __shfl_xor(acc, 32, 64);
  if (lane < 16) h1[wid * WSZ + c] = fmaxf(acc + bias1[c], 0.f);
}

// ---------------- 6a) dense layer-2 projection: H2[n][p*16+c] -----------------
// H2 has the same [N][NC] layout as H (c in [10,16) zero-filled) so the
// aggregation gather is identical 64B-aligned-line traffic.
__global__ __launch_bounds__(256) void k_h2(const float* __restrict__ h1,
                                            const float* __restrict__ w2,
                                            float* __restrict__ H2) {
  __shared__ float w2s[RR * WSZ * CC];                   // 21.1 KB
  for (int i = threadIdx.x; i < RR * WSZ * CC; i += 256) w2s[i] = w2[i];
  __syncthreads();
  int idx = blockIdx.x * 256 + threadIdx.x;              // NN*NC = 26,400,000 exact
  int n = idx / NC, j = idx - n * NC;
  int p = j >> 4, c = j & 15;
  float dot = 0.f;
  if (c < CC) {
    const float* hp = h1 + n * WSZ;                      // L1/L2 broadcast within wave
    const float* wp = w2s + p * WSZ * CC + c;
#pragma unroll
    for (int i2 = 0; i2 < WSZ; ++i2) dot += hp[i2] * wp[i2 * CC];
  }
  H2[idx] = dot;
}

// ---------------- 6b) layer-2 aggregation: pure gather (no shuffles/edge) -----
__global__ __launch_bounds__(256) void k_agg2(const uint2* __restrict__ recs,
                                              const int* __restrict__ offs,
                                              const float* __restrict__ H2,
                                              const float* __restrict__ bias2,
                                              float* __restrict__ out) {
  int wid  = (blockIdx.x * 256 + threadIdx.x) >> 6;      // exactly NN waves
  int lane = threadIdx.x & 63;
  int grp = lane >> 4, c = lane & 15;
  int beg = offs[wid], end = offs[wid + 1];
  float acc = 0.f;
  for (int e = beg + grp; e < end; e += 4) {
    uint2 r = recs[e];
    int o = r.x & 0xFFFF, p = r.x >> 16;
    float val = __uint_as_float(r.y);
    acc += val * H2[(size_t)o * NC + p * WSZ + c];       // 64B-aligned cacheline
  }
  acc += __shfl_xor(acc, 16, 64);
  acc += __shfl_xor(acc, 32, 64);
  if (lane < CC) out[wid * CC + c] = acc + bias2[c];
}

// ---------------- launcher ----------------
extern "C" void kernel_launch(void* const* d_in, const int* in_sizes, int n_in,
                              void* d_out, int out_size, void* d_ws, size_t ws_size,
                              hipStream_t stream) {
  const float* emb = (const float*)d_in[0];
  const float* w1  = (const float*)d_in[1];
  const float* b1  = (const float*)d_in[2];
  const float* w2  = (const float*)d_in[3];
  const float* b2  = (const float*)d_in[4];
  const float* ev  = (const float*)d_in[5];
  const int*   es  = (const int*)d_in[6];
  const int*   ep  = (const int*)d_in[7];
  const int*   eo  = (const int*)d_in[8];
  float* out = (float*)d_out;

  char* ws = (char*)d_ws;
  size_t off = 0;
  auto alloc = [&](size_t bytes) -> void* {
    void* p = ws + off;
    off = (off + bytes + 255) & ~(size_t)255;
    return p;
  };
  __hip_bfloat16* Abf = (__hip_bfloat16*)alloc((size_t)NN * DD * 2);   // 160 MB
  __hip_bfloat16* Bt  = (__hip_bfloat16*)alloc((size_t)NCP * DD * 2);  //   2 MB
  float* H    = (float*)alloc((size_t)NN * NC * 4);                    // 105.6 MB
  float* h1   = (float*)alloc((size_t)NN * WSZ * 4);                   //   3.2 MB
  uint2* recs = (uint2*)alloc((size_t)EE * 8);                         //  25.6 MB
  int* counts = (int*)alloc((size_t)NN * 4);
  int* offs   = (int*)alloc((size_t)(NN + 1) * 4);
  int* ptr    = (int*)alloc((size_t)(NN + 1) * 4);
  // H2 aliases Abf: Abf (160 MB) is dead after k_gemm; H2 needs 105.6 MB.
  float* H2 = (float*)Abf;

  hipMemsetAsync(counts, 0, (size_t)NN * 4, stream);

  k_conv_a  <<<78125, 256, 0, stream>>>((const float4*)emb, (ushort4*)Abf);
  k_build_bt<<<4000,  256, 0, stream>>>(w1, Bt);
  k_hist    <<<12500, 256, 0, stream>>>(es, counts);
  k_scan    <<<1,    1024, 0, stream>>>(counts, offs, ptr);
  k_scatter <<<12500, 256, 0, stream>>>(es, ep, eo, ev, ptr, recs);
  dim3 gg(391, 5);
  k_gemm    <<<gg,    256, 0, stream>>>(Abf, Bt, H);
  k_agg1    <<<12500, 256, 0, stream>>>(recs, offs, H, b1, h1);
  k_h2      <<<103125,256, 0, stream>>>(h1, w2, H2);
  k_agg2    <<<12500, 256, 0, stream>>>(recs, offs, H2, b2, out);
}

// Round 3
// 1455.568 us; speedup vs baseline: 1.0149x; 1.0149x over previous
//
#include <hip/hip_runtime.h>
#include <hip/hip_bf16.h>
#include <stdint.h>

// Problem constants
#define NN 50000            // nodes
#define RR 33               // relations
#define EE 3200000          // edges
#define DD 1600             // emb dim
#define WSZ 16              // weights_size
#define CC 10               // classes
#define NC (RR*WSZ)         // 528 columns of H / H2
#define NCP 640             // padded to 5 * 128 column tiles

// Bucketed-scatter params
#define NBK 64              // bucket slots (49 used)
#define BSH 10              // bucket = s >> 10  (1024 nodes/bucket)
#define NBUSED ((NN + (1<<BSH) - 1) >> BSH)   // 49
#define MEDG 4096           // edges staged per block in pass A

typedef __attribute__((ext_vector_type(8))) short bfrag;   // 8 bf16 = 4 VGPRs
typedef __attribute__((ext_vector_type(4))) float f32x4;

__device__ __forceinline__ unsigned short f2bf(float f) {
  union { float f; unsigned u; } v; v.f = f;
  unsigned r = v.u + 0x7FFF + ((v.u >> 16) & 1);   // RNE, inputs are finite
  return (unsigned short)(r >> 16);
}

// ---------------- 1) emb fp32 -> bf16 (A matrix) ----------------
__global__ __launch_bounds__(256) void k_conv_a(const float4* __restrict__ src,
                                                ushort4* __restrict__ dst) {
  size_t i = (size_t)blockIdx.x * 256 + threadIdx.x;   // exactly 20,000,000 threads
  float4 v = src[i];
  ushort4 o;
  o.x = f2bf(v.x); o.y = f2bf(v.y); o.z = f2bf(v.z); o.w = f2bf(v.w);
  dst[i] = o;
}

// ---------------- 2) build B^T bf16 [NCP][DD], Bt[n][k] = w1[n>>4][k][n&15] ----
__global__ __launch_bounds__(256) void k_build_bt(const float* __restrict__ w1,
                                                  __hip_bfloat16* __restrict__ bt) {
  int idx = blockIdx.x * 256 + threadIdx.x;            // NCP*DD = 1,024,000 exact
  int n = idx / DD, k = idx - n * DD;
  float v = 0.f;
  if (n < NC) {
    int r = n >> 4, o = n & 15;
    v = w1[((size_t)r * DD + k) * WSZ + o];
  }
  unsigned short b = f2bf(v);
  *reinterpret_cast<unsigned short*>(&bt[idx]) = b;
}

// ---------------- 3a) histogram of edge_s ----------------
__global__ __launch_bounds__(256) void k_hist(const int* __restrict__ es,
                                              int* __restrict__ counts) {
  int i = blockIdx.x * 256 + threadIdx.x;              // EE exact
  atomicAdd(&counts[es[i]], 1);
}

// ---------------- 3b) exclusive scan (single block) + bucket base ptrs --------
__global__ __launch_bounds__(1024) void k_scan(const int* __restrict__ counts,
                                               int* __restrict__ offs,
                                               int* __restrict__ ptr,
                                               int* __restrict__ bptr) {
  __shared__ int part[1024];
  int t = threadIdx.x;
  const int CH = 49;                                   // 49*1024 >= NN
  int base = t * CH;
  int s = 0;
  for (int j = 0; j < CH; ++j) { int i = base + j; if (i < NN) s += counts[i]; }
  part[t] = s;
  __syncthreads();
  for (int off = 1; off < 1024; off <<= 1) {
    int v = (t >= off) ? part[t - off] : 0;
    __syncthreads();
    part[t] += v;
    __syncthreads();
  }
  int running = part[t] - s;                           // exclusive prefix of this chunk
  for (int j = 0; j < CH; ++j) {
    int i = base + j;
    if (i < NN) { offs[i] = running; ptr[i] = running; running += counts[i]; }
  }
  if (t == 0) offs[NN] = part[1023];
  __syncthreads();                                     // global W->R within block is coherent
  if (t < NBK) {
    int node = t << BSH; if (node > NN) node = NN;
    bptr[t] = offs[node];
  }
}

// ---------------- 3c pass A) LDS-staged bucket binning ------------------------
// tmp records grouped by bucket (s>>10); r.x = o | p<<16 | (s&1023)<<22
__global__ __launch_bounds__(256) void k_bucket(const int* __restrict__ es,
                                                const int* __restrict__ ep,
                                                const int* __restrict__ eo,
                                                const float* __restrict__ ev,
                                                int* __restrict__ bptr,
                                                uint2* __restrict__ tmp) {
  __shared__ int lhist[NBK];
  __shared__ int lofs[NBK];
  __shared__ int lcur[NBK];
  __shared__ int lbase[NBK];
  __shared__ uint2 stage[MEDG];
  __shared__ unsigned char sbk[MEDG];
  int tid = threadIdx.x;
  int e0 = blockIdx.x * MEDG;
  int n = EE - e0; if (n > MEDG) n = MEDG;
  for (int i = tid; i < NBK; i += 256) lhist[i] = 0;
  __syncthreads();
  for (int i = tid; i < n; i += 256)
    atomicAdd(&lhist[es[e0 + i] >> BSH], 1);
  __syncthreads();
  if (tid == 0) {
    int run = 0;
    for (int b = 0; b < NBK; ++b) { lofs[b] = run; run += lhist[b]; }
  }
  __syncthreads();
  if (tid < NBK) {
    lcur[tid] = lofs[tid];
    lbase[tid] = lhist[tid] ? atomicAdd(&bptr[tid], lhist[tid]) : 0;
  }
  __syncthreads();
  for (int i = tid; i < n; i += 256) {
    int s = es[e0 + i];
    int b = s >> BSH;
    int pos = atomicAdd(&lcur[b], 1);
    uint2 r;
    r.x = (unsigned)eo[e0 + i] | ((unsigned)ep[e0 + i] << 16)
        | ((unsigned)(s & 1023) << 22);
    r.y = __float_as_uint(ev[e0 + i]);
    stage[pos] = r;
    sbk[pos] = (unsigned char)b;
  }
  __syncthreads();
  for (int i = tid; i < n; i += 256) {                 // grouped -> ~sequential writes
    int b = sbk[i];
    tmp[lbase[b] + (i - lofs[b])] = stage[i];
  }
}

// ---------------- 3c pass B) within-bucket CSR scatter (L2-resident) ----------
__global__ __launch_bounds__(1024) void k_scatter2(const uint2* __restrict__ tmp,
                                                   const int* __restrict__ offs,
                                                   int* __restrict__ ptr,
                                                   uint2* __restrict__ recs) {
  int b = blockIdx.x;                                  // NBUSED blocks
  int n0 = b << BSH, n1 = (b + 1) << BSH;
  if (n1 > NN) n1 = NN;
  int start = offs[n0], endv = offs[n1];
  for (int i = start + (int)threadIdx.x; i < endv; i += 1024) {
    uint2 r = tmp[i];
    int s = n0 + (int)(r.x >> 22);
    int pos = atomicAdd(&ptr[s], 1);
    recs[pos] = r;                                     // random within ~512KB: L2 absorbs
  }
}

// ---------------- 4) GEMM: H[NN][NC] = A[NN][DD] @ B[DD][NC]  (bf16 MFMA) ------
#define BM 128
#define BN 128
#define BK 32

__global__ __launch_bounds__(256) void k_gemm(const __hip_bfloat16* __restrict__ A,
                                              const __hip_bfloat16* __restrict__ Bt,
                                              float* __restrict__ H) {
  __shared__ __align__(16) __hip_bfloat16 As[BM * BK];   // [row][k]
  __shared__ __align__(16) __hip_bfloat16 Bs[BN * BK];   // [col][k] (Bt layout)
  int tid  = threadIdx.x;
  int wave = tid >> 6, lane = tid & 63;
  int m0 = blockIdx.x * BM;
  int n0 = blockIdx.y * BN;
  int wm = (wave >> 1) * 64, wn = (wave & 1) * 64;       // 2x2 wave quadrants
  int ld = lane & 15, quad = lane >> 4;

  f32x4 acc[4][4] = {};

  for (int k0 = 0; k0 < DD; k0 += BK) {
    __syncthreads();
#pragma unroll
    for (int j = 0; j < 2; ++j) {                        // stage A tile: 512 x 16B
      int idx = j * 256 + tid;
      int row = idx >> 2;
      int kc  = (idx & 3) * 8;
      int grow = m0 + row; if (grow > NN - 1) grow = NN - 1;
      const __hip_bfloat16* gp = A + (size_t)grow * DD + k0 + kc;
      __builtin_amdgcn_global_load_lds(
          (const __attribute__((address_space(1))) void*)gp,
          (__attribute__((address_space(3))) void*)(As + idx * 8), 16, 0, 0);
    }
#pragma unroll
    for (int j = 0; j < 2; ++j) {                        // stage Bt tile: 512 x 16B
      int idx = j * 256 + tid;
      int col = idx >> 2;
      int kc  = (idx & 3) * 8;
      const __hip_bfloat16* gp = Bt + (size_t)(n0 + col) * DD + k0 + kc;
      __builtin_amdgcn_global_load_lds(
          (const __attribute__((address_space(1))) void*)gp,
          (__attribute__((address_space(3))) void*)(Bs + idx * 8), 16, 0, 0);
    }
    __syncthreads();                                     // compiler drains vmcnt here

    bfrag af[4], bf[4];
#pragma unroll
    for (int mi = 0; mi < 4; ++mi)
      af[mi] = *(const bfrag*)(As + (wm + mi * 16 + ld) * BK + quad * 8);
#pragma unroll
    for (int ni = 0; ni < 4; ++ni)
      bf[ni] = *(const bfrag*)(Bs + (wn + ni * 16 + ld) * BK + quad * 8);
#pragma unroll
    for (int mi = 0; mi < 4; ++mi)
#pragma unroll
      for (int ni = 0; ni < 4; ++ni)
        acc[mi][ni] = __builtin_amdgcn_mfma_f32_16x16x32_bf16(af[mi], bf[ni],
                                                              acc[mi][ni], 0, 0, 0);
  }

#pragma unroll
  for (int mi = 0; mi < 4; ++mi)
#pragma unroll
    for (int ni = 0; ni < 4; ++ni) {
      int col = n0 + wn + ni * 16 + ld;
      if (col >= NC) continue;
#pragma unroll
      for (int r = 0; r < 4; ++r) {
        int row = m0 + wm + mi * 16 + quad * 4 + r;      // C/D: col=lane&15, row=quad*4+reg
        if (row < NN) H[(size_t)row * NC + col] = acc[mi][ni][r];
      }
    }
}

// ---------------- 5) layer-1 aggregation: one wave per destination node -------
__global__ __launch_bounds__(256) void k_agg1(const uint2* __restrict__ recs,
                                              const int* __restrict__ offs,
                                              const float* __restrict__ H,
                                              const float* __restrict__ bias1,
                                              float* __restrict__ h1) {
  int wid  = (blockIdx.x * 256 + threadIdx.x) >> 6;      // exactly NN waves
  int lane = threadIdx.x & 63;
  int grp = lane >> 4, c = lane & 15;
  int beg = offs[wid], end = offs[wid + 1];
  float acc = 0.f;
  for (int e = beg + grp; e < end; e += 4) {
    uint2 r = recs[e];                                   // broadcast within group
    int o = r.x & 0xFFFF, p = (r.x >> 16) & 0x3F;
    float val = __uint_as_float(r.y);
    acc += val * H[(size_t)o * NC + p * WSZ + c];        // 64B-aligned cacheline
  }
  acc += __shfl_xor(acc, 16, 64);
  acc += __shfl_xor(acc, 32, 64);
  if (lane < 16) h1[wid * WSZ + c] = fmaxf(acc + bias1[c], 0.f);
}

// ---------------- 6a) dense layer-2 projection: H2[n][p*16+c] -----------------
__global__ __launch_bounds__(256) void k_h2(const float* __restrict__ h1,
                                            const float* __restrict__ w2,
                                            float* __restrict__ H2) {
  __shared__ float w2s[RR * WSZ * CC];                   // 21.1 KB
  for (int i = threadIdx.x; i < RR * WSZ * CC; i += 256) w2s[i] = w2[i];
  __syncthreads();
  int idx = blockIdx.x * 256 + threadIdx.x;              // NN*NC = 26,400,000 exact
  int n = idx / NC, j = idx - n * NC;
  int p = j >> 4, c = j & 15;
  float dot = 0.f;
  if (c < CC) {
    const float* hp = h1 + n * WSZ;
    const float* wp = w2s + p * WSZ * CC + c;
#pragma unroll
    for (int i2 = 0; i2 < WSZ; ++i2) dot += hp[i2] * wp[i2 * CC];
  }
  H2[idx] = dot;
}

// ---------------- 6b) layer-2 aggregation: pure gather ------------------------
__global__ __launch_bounds__(256) void k_agg2(const uint2* __restrict__ recs,
                                              const int* __restrict__ offs,
                                              const float* __restrict__ H2,
                                              const float* __restrict__ bias2,
                                              float* __restrict__ out) {
  int wid  = (blockIdx.x * 256 + threadIdx.x) >> 6;      // exactly NN waves
  int lane = threadIdx.x & 63;
  int grp = lane >> 4, c = lane & 15;
  int beg = offs[wid], end = offs[wid + 1];
  float acc = 0.f;
  for (int e = beg + grp; e < end; e += 4) {
    uint2 r = recs[e];
    int o = r.x & 0xFFFF, p = (r.x >> 16) & 0x3F;
    float val = __uint_as_float(r.y);
    acc += val * H2[(size_t)o * NC + p * WSZ + c];       // 64B-aligned cacheline
  }
  acc += __shfl_xor(acc, 16, 64);
  acc += __shfl_xor(acc, 32, 64);
  if (lane < CC) out[wid * CC + c] = acc + bias2[c];
}

// ---------------- launcher ----------------
extern "C" void kernel_launch(void* const* d_in, const int* in_sizes, int n_in,
                              void* d_out, int out_size, void* d_ws, size_t ws_size,
                              hipStream_t stream) {
  const float* emb = (const float*)d_in[0];
  const float* w1  = (const float*)d_in[1];
  const float* b1  = (const float*)d_in[2];
  const float* w2  = (const float*)d_in[3];
  const float* b2  = (const float*)d_in[4];
  const float* ev  = (const float*)d_in[5];
  const int*   es  = (const int*)d_in[6];
  const int*   ep  = (const int*)d_in[7];
  const int*   eo  = (const int*)d_in[8];
  float* out = (float*)d_out;

  char* ws = (char*)d_ws;
  size_t off = 0;
  auto alloc = [&](size_t bytes) -> void* {
    void* p = ws + off;
    off = (off + bytes + 255) & ~(size_t)255;
    return p;
  };
  __hip_bfloat16* Abf = (__hip_bfloat16*)alloc((size_t)NN * DD * 2);   // 160 MB
  __hip_bfloat16* Bt  = (__hip_bfloat16*)alloc((size_t)NCP * DD * 2);  //   2 MB
  float* H    = (float*)alloc((size_t)NN * NC * 4);                    // 105.6 MB
  float* h1   = (float*)alloc((size_t)NN * WSZ * 4);                   //   3.2 MB
  uint2* recs = (uint2*)alloc((size_t)EE * 8);                         //  25.6 MB
  int* counts = (int*)alloc((size_t)NN * 4);
  int* offs   = (int*)alloc((size_t)(NN + 1) * 4);
  int* ptr    = (int*)alloc((size_t)(NN + 1) * 4);
  int* bptr   = (int*)alloc((size_t)NBK * 4);
  // tmp aliases H (dead until k_gemm); H2 aliases Abf (dead after k_gemm)
  uint2* tmp = (uint2*)H;
  float* H2  = (float*)Abf;

  hipMemsetAsync(counts, 0, (size_t)NN * 4, stream);

  k_conv_a  <<<78125, 256, 0, stream>>>((const float4*)emb, (ushort4*)Abf);
  k_build_bt<<<4000,  256, 0, stream>>>(w1, Bt);
  k_hist    <<<12500, 256, 0, stream>>>(es, counts);
  k_scan    <<<1,    1024, 0, stream>>>(counts, offs, ptr, bptr);
  k_bucket  <<<(EE + MEDG - 1) / MEDG, 256, 0, stream>>>(es, ep, eo, ev, bptr, tmp);
  k_scatter2<<<NBUSED, 1024, 0, stream>>>(tmp, offs, ptr, recs);
  dim3 gg(391, 5);
  k_gemm    <<<gg,    256, 0, stream>>>(Abf, Bt, H);
  k_agg1    <<<12500, 256, 0, stream>>>(recs, offs, H, b1, h1);
  k_h2      <<<103125,256, 0, stream>>>(h1, w2, H2);
  k_agg2    <<<12500, 256, 0, stream>>>(recs, offs, H2, b2, out);
}

// Round 4
// 1274.307 us; speedup vs baseline: 1.1592x; 1.1422x over previous
//
#include <hip/hip_runtime.h>
#include <hip/hip_bf16.h>
#include <stdint.h>

// Problem constants
#define NN 50000            // nodes
#define RR 33               // relations
#define EE 3200000          // edges
#define DD 1600             // emb dim
#define WSZ 16              // weights_size
#define CC 10               // classes
#define NC (RR*WSZ)         // 528 columns of H / H2
#define NCP 640             // padded to 5 * 128 column tiles

// Bucketed-scatter params
#define NBK 64              // bucket slots (49 used)
#define BSH 10              // bucket = s >> 10  (1024 nodes/bucket)
#define NBUSED ((NN + (1<<BSH) - 1) >> BSH)   // 49
#define MEDG 4096           // edges staged per block in pass A

typedef __attribute__((ext_vector_type(8))) short bfrag;   // 8 bf16 = 4 VGPRs
typedef __attribute__((ext_vector_type(4))) float f32x4;

__device__ __forceinline__ unsigned short f2bf(float f) {
  union { float f; unsigned u; } v; v.f = f;
  unsigned r = v.u + 0x7FFF + ((v.u >> 16) & 1);   // RNE, inputs are finite
  return (unsigned short)(r >> 16);
}
__device__ __forceinline__ float bf2f(unsigned short h) {
  union { unsigned u; float f; } v; v.u = ((unsigned)h) << 16;
  return v.f;
}

// ---------------- 1) emb fp32 -> bf16 (A matrix) ----------------
__global__ __launch_bounds__(256) void k_conv_a(const float4* __restrict__ src,
                                                ushort4* __restrict__ dst) {
  size_t i = (size_t)blockIdx.x * 256 + threadIdx.x;   // exactly 20,000,000 threads
  float4 v = src[i];
  ushort4 o;
  o.x = f2bf(v.x); o.y = f2bf(v.y); o.z = f2bf(v.z); o.w = f2bf(v.w);
  dst[i] = o;
}

// ---------------- 2) build B^T bf16 [NCP][DD], Bt[n][k] = w1[n>>4][k][n&15] ----
__global__ __launch_bounds__(256) void k_build_bt(const float* __restrict__ w1,
                                                  __hip_bfloat16* __restrict__ bt) {
  int idx = blockIdx.x * 256 + threadIdx.x;            // NCP*DD = 1,024,000 exact
  int n = idx / DD, k = idx - n * DD;
  float v = 0.f;
  if (n < NC) {
    int r = n >> 4, o = n & 15;
    v = w1[((size_t)r * DD + k) * WSZ + o];
  }
  unsigned short b = f2bf(v);
  *reinterpret_cast<unsigned short*>(&bt[idx]) = b;
}

// ---------------- 3a) histogram of edge_s ----------------
__global__ __launch_bounds__(256) void k_hist(const int* __restrict__ es,
                                              int* __restrict__ counts) {
  int i = blockIdx.x * 256 + threadIdx.x;              // EE exact
  atomicAdd(&counts[es[i]], 1);
}

// ---------------- 3b-i) per-1024-chunk partial sums (coalesced) ---------------
__global__ __launch_bounds__(256) void k_part(const int* __restrict__ counts,
                                              int* __restrict__ part) {
  int b = blockIdx.x, t = threadIdx.x;                 // NBUSED blocks
  int base = b << BSH;
  int s = 0;
  for (int j = t; j < (1 << BSH); j += 256) {
    int i = base + j; if (i < NN) s += counts[i];
  }
#pragma unroll
  for (int off = 32; off; off >>= 1) s += __shfl_down(s, off, 64);
  __shared__ int ws[4];
  if ((t & 63) == 0) ws[t >> 6] = s;
  __syncthreads();
  if (t == 0) part[b] = ws[0] + ws[1] + ws[2] + ws[3];
}

// ---------------- 3b-ii) scan 49 partials (one wave) --------------------------
__global__ __launch_bounds__(64) void k_scan2(const int* __restrict__ part,
                                              int* __restrict__ bbase,
                                              int* __restrict__ bptr,
                                              int* __restrict__ offs) {
  int t = threadIdx.x;
  int v = (t < NBUSED) ? part[t] : 0;
  int incl = v;
#pragma unroll
  for (int off = 1; off < 64; off <<= 1) {
    int x = __shfl_up(incl, off, 64);
    if (t >= off) incl += x;
  }
  int excl = incl - v;
  if (t < NBUSED) { bbase[t] = excl; bptr[t] = excl; }
  else if (t < NBK) bptr[t] = EE;
  if (t == 63) offs[NN] = EE;                          // all edges counted
}

// ---------------- 3b-iii) per-chunk exclusive scan -> offs/ptr ----------------
__global__ __launch_bounds__(1024) void k_offs(const int* __restrict__ counts,
                                               const int* __restrict__ bbase,
                                               int* __restrict__ offs,
                                               int* __restrict__ ptr) {
  __shared__ int sc[1024];
  int b = blockIdx.x, t = threadIdx.x;                 // NBUSED blocks x 1024
  int node = (b << BSH) + t;
  int v = (node < NN) ? counts[node] : 0;
  sc[t] = v;
  __syncthreads();
  for (int off = 1; off < 1024; off <<= 1) {
    int x = (t >= off) ? sc[t - off] : 0;
    __syncthreads();
    sc[t] += x;
    __syncthreads();
  }
  int excl = sc[t] - v + bbase[b];
  if (node < NN) { offs[node] = excl; ptr[node] = excl; }
}

// ---------------- 3c pass A) LDS-staged bucket binning ------------------------
// tmp records grouped by bucket (s>>10); r.x = o | p<<16 | (s&1023)<<22
__global__ __launch_bounds__(256) void k_bucket(const int* __restrict__ es,
                                                const int* __restrict__ ep,
                                                const int* __restrict__ eo,
                                                const float* __restrict__ ev,
                                                int* __restrict__ bptr,
                                                uint2* __restrict__ tmp) {
  __shared__ int lhist[NBK];
  __shared__ int lofs[NBK];
  __shared__ int lcur[NBK];
  __shared__ int lbase[NBK];
  __shared__ uint2 stage[MEDG];
  __shared__ unsigned char sbk[MEDG];
  int tid = threadIdx.x;
  int e0 = blockIdx.x * MEDG;
  int n = EE - e0; if (n > MEDG) n = MEDG;
  for (int i = tid; i < NBK; i += 256) lhist[i] = 0;
  __syncthreads();
  for (int i = tid; i < n; i += 256)
    atomicAdd(&lhist[es[e0 + i] >> BSH], 1);
  __syncthreads();
  if (tid == 0) {
    int run = 0;
    for (int b = 0; b < NBK; ++b) { lofs[b] = run; run += lhist[b]; }
  }
  __syncthreads();
  if (tid < NBK) {
    lcur[tid] = lofs[tid];
    lbase[tid] = lhist[tid] ? atomicAdd(&bptr[tid], lhist[tid]) : 0;
  }
  __syncthreads();
  for (int i = tid; i < n; i += 256) {
    int s = es[e0 + i];
    int b = s >> BSH;
    int pos = atomicAdd(&lcur[b], 1);
    uint2 r;
    r.x = (unsigned)eo[e0 + i] | ((unsigned)ep[e0 + i] << 16)
        | ((unsigned)(s & 1023) << 22);
    r.y = __float_as_uint(ev[e0 + i]);
    stage[pos] = r;
    sbk[pos] = (unsigned char)b;
  }
  __syncthreads();
  for (int i = tid; i < n; i += 256) {                 // grouped -> ~sequential writes
    int b = sbk[i];
    tmp[lbase[b] + (i - lofs[b])] = stage[i];
  }
}

// ---------------- 3c pass B) within-bucket CSR scatter (L2-resident) ----------
#define SBPB 8               // sub-blocks per bucket
__global__ __launch_bounds__(256) void k_scatter2(const uint2* __restrict__ tmp,
                                                  const int* __restrict__ offs,
                                                  int* __restrict__ ptr,
                                                  uint2* __restrict__ recs) {
  int b = blockIdx.x;                                  // NBUSED x SBPB grid
  int n0 = b << BSH, n1 = (b + 1) << BSH;
  if (n1 > NN) n1 = NN;
  int start = offs[n0], endv = offs[n1];
  int tid = blockIdx.y * 256 + (int)threadIdx.x;
  for (int i = start + tid; i < endv; i += SBPB * 256) {
    uint2 r = tmp[i];
    int s = n0 + (int)(r.x >> 22);
    int pos = atomicAdd(&ptr[s], 1);
    recs[pos] = r;                                     // random within ~512KB: L2 absorbs
  }
}

// ---------------- 4) GEMM: H[NN][NC] = A @ B, bf16 in, bf16 out ---------------
#define BM 128
#define BN 128
#define BK 32

__global__ __launch_bounds__(256) void k_gemm(const __hip_bfloat16* __restrict__ A,
                                              const __hip_bfloat16* __restrict__ Bt,
                                              __hip_bfloat16* __restrict__ Hb) {
  __shared__ __align__(16) __hip_bfloat16 As[BM * BK];   // [row][k]
  __shared__ __align__(16) __hip_bfloat16 Bs[BN * BK];   // [col][k] (Bt layout)
  int tid  = threadIdx.x;
  int wave = tid >> 6, lane = tid & 63;
  int n0 = blockIdx.x * BN;                              // n-tile FAST: A strip shared
  int m0 = blockIdx.y * BM;                              // by 5 adjacent blocks (L2/L3)
  int wm = (wave >> 1) * 64, wn = (wave & 1) * 64;       // 2x2 wave quadrants
  int ld = lane & 15, quad = lane >> 4;

  f32x4 acc[4][4] = {};

  for (int k0 = 0; k0 < DD; k0 += BK) {
    __syncthreads();
#pragma unroll
    for (int j = 0; j < 2; ++j) {                        // stage A tile: 512 x 16B
      int idx = j * 256 + tid;
      int row = idx >> 2;
      int kc  = (idx & 3) * 8;
      int grow = m0 + row; if (grow > NN - 1) grow = NN - 1;
      const __hip_bfloat16* gp = A + (size_t)grow * DD + k0 + kc;
      __builtin_amdgcn_global_load_lds(
          (const __attribute__((address_space(1))) void*)gp,
          (__attribute__((address_space(3))) void*)(As + idx * 8), 16, 0, 0);
    }
#pragma unroll
    for (int j = 0; j < 2; ++j) {                        // stage Bt tile: 512 x 16B
      int idx = j * 256 + tid;
      int col = idx >> 2;
      int kc  = (idx & 3) * 8;
      const __hip_bfloat16* gp = Bt + (size_t)(n0 + col) * DD + k0 + kc;
      __builtin_amdgcn_global_load_lds(
          (const __attribute__((address_space(1))) void*)gp,
          (__attribute__((address_space(3))) void*)(Bs + idx * 8), 16, 0, 0);
    }
    __syncthreads();                                     // compiler drains vmcnt here

    bfrag af[4], bf[4];
#pragma unroll
    for (int mi = 0; mi < 4; ++mi)
      af[mi] = *(const bfrag*)(As + (wm + mi * 16 + ld) * BK + quad * 8);
#pragma unroll
    for (int ni = 0; ni < 4; ++ni)
      bf[ni] = *(const bfrag*)(Bs + (wn + ni * 16 + ld) * BK + quad * 8);
#pragma unroll
    for (int mi = 0; mi < 4; ++mi)
#pragma unroll
      for (int ni = 0; ni < 4; ++ni)
        acc[mi][ni] = __builtin_amdgcn_mfma_f32_16x16x32_bf16(af[mi], bf[ni],
                                                              acc[mi][ni], 0, 0, 0);
  }

#pragma unroll
  for (int mi = 0; mi < 4; ++mi)
#pragma unroll
    for (int ni = 0; ni < 4; ++ni) {
      int col = n0 + wn + ni * 16 + ld;
      if (col >= NC) continue;
#pragma unroll
      for (int r = 0; r < 4; ++r) {
        int row = m0 + wm + mi * 16 + quad * 4 + r;      // C/D: col=lane&15, row=quad*4+reg
        if (row < NN)
          *reinterpret_cast<unsigned short*>(&Hb[(size_t)row * NC + col]) =
              f2bf(acc[mi][ni][r]);
      }
    }
}

// ---------------- 5) layer-1 aggregation: one wave per destination node -------
__global__ __launch_bounds__(256) void k_agg1(const uint2* __restrict__ recs,
                                              const int* __restrict__ offs,
                                              const __hip_bfloat16* __restrict__ Hb,
                                              const float* __restrict__ bias1,
                                              float* __restrict__ h1) {
  int wid  = (blockIdx.x * 256 + threadIdx.x) >> 6;      // exactly NN waves
  int lane = threadIdx.x & 63;
  int grp = lane >> 4, c = lane & 15;
  int beg = offs[wid], end = offs[wid + 1];
  float acc = 0.f;
  for (int e = beg + grp; e < end; e += 4) {
    uint2 r = recs[e];                                   // broadcast within group
    int o = r.x & 0xFFFF, p = (r.x >> 16) & 0x3F;
    float val = __uint_as_float(r.y);
    unsigned short h = *reinterpret_cast<const unsigned short*>(
        &Hb[(size_t)o * NC + p * WSZ + c]);              // 32B-aligned segment
    acc += val * bf2f(h);
  }
  acc += __shfl_xor(acc, 16, 64);
  acc += __shfl_xor(acc, 32, 64);
  if (lane < 16) h1[wid * WSZ + c] = fmaxf(acc + bias1[c], 0.f);
}

// ---------------- 6a) dense layer-2 projection: H2[n][p*16+c], bf16 out -------
__global__ __launch_bounds__(256) void k_h2(const float* __restrict__ h1,
                                            const float* __restrict__ w2,
                                            __hip_bfloat16* __restrict__ H2) {
  __shared__ float w2s[RR * WSZ * CC];                   // 21.1 KB
  for (int i = threadIdx.x; i < RR * WSZ * CC; i += 256) w2s[i] = w2[i];
  __syncthreads();
  int idx = blockIdx.x * 256 + threadIdx.x;              // NN*NC = 26,400,000 exact
  int n = idx / NC, j = idx - n * NC;
  int p = j >> 4, c = j & 15;
  float dot = 0.f;
  if (c < CC) {
    const float* hp = h1 + n * WSZ;
    const float* wp = w2s + p * WSZ * CC + c;
#pragma unroll
    for (int i2 = 0; i2 < WSZ; ++i2) dot += hp[i2] * wp[i2 * CC];
  }
  *reinterpret_cast<unsigned short*>(&H2[idx]) = f2bf(dot);
}

// ---------------- 6b) layer-2 aggregation: pure gather ------------------------
__global__ __launch_bounds__(256) void k_agg2(const uint2* __restrict__ recs,
                                              const int* __restrict__ offs,
                                              const __hip_bfloat16* __restrict__ H2,
                                              const float* __restrict__ bias2,
                                              float* __restrict__ out) {
  int wid  = (blockIdx.x * 256 + threadIdx.x) >> 6;      // exactly NN waves
  int lane = threadIdx.x & 63;
  int grp = lane >> 4, c = lane & 15;
  int beg = offs[wid], end = offs[wid + 1];
  float acc = 0.f;
  for (int e = beg + grp; e < end; e += 4) {
    uint2 r = recs[e];
    int o = r.x & 0xFFFF, p = (r.x >> 16) & 0x3F;
    float val = __uint_as_float(r.y);
    unsigned short h = *reinterpret_cast<const unsigned short*>(
        &H2[(size_t)o * NC + p * WSZ + c]);
    acc += val * bf2f(h);
  }
  acc += __shfl_xor(acc, 16, 64);
  acc += __shfl_xor(acc, 32, 64);
  if (lane < CC) out[wid * CC + c] = acc + bias2[c];
}

// ---------------- launcher ----------------
extern "C" void kernel_launch(void* const* d_in, const int* in_sizes, int n_in,
                              void* d_out, int out_size, void* d_ws, size_t ws_size,
                              hipStream_t stream) {
  const float* emb = (const float*)d_in[0];
  const float* w1  = (const float*)d_in[1];
  const float* b1  = (const float*)d_in[2];
  const float* w2  = (const float*)d_in[3];
  const float* b2  = (const float*)d_in[4];
  const float* ev  = (const float*)d_in[5];
  const int*   es  = (const int*)d_in[6];
  const int*   ep  = (const int*)d_in[7];
  const int*   eo  = (const int*)d_in[8];
  float* out = (float*)d_out;

  char* ws = (char*)d_ws;
  size_t off = 0;
  auto alloc = [&](size_t bytes) -> void* {
    void* p = ws + off;
    off = (off + bytes + 255) & ~(size_t)255;
    return p;
  };
  __hip_bfloat16* Abf = (__hip_bfloat16*)alloc((size_t)NN * DD * 2);   // 160 MB
  __hip_bfloat16* Bt  = (__hip_bfloat16*)alloc((size_t)NCP * DD * 2);  //   2 MB
  __hip_bfloat16* Hb  = (__hip_bfloat16*)alloc((size_t)NN * NC * 2);   // 52.8 MB
  float* h1   = (float*)alloc((size_t)NN * WSZ * 4);                   //  3.2 MB
  uint2* recs = (uint2*)alloc((size_t)EE * 8);                         // 25.6 MB
  int* counts = (int*)alloc((size_t)NN * 4);
  int* offs   = (int*)alloc((size_t)(NN + 1) * 4);
  int* ptr    = (int*)alloc((size_t)(NN + 1) * 4);
  int* bptr   = (int*)alloc((size_t)NBK * 4);
  int* part   = (int*)alloc((size_t)NBUSED * 4);
  int* bbase  = (int*)alloc((size_t)NBUSED * 4);
  // tmp aliases Hb (dead until k_gemm); H2 aliases Abf (dead after k_gemm)
  uint2* tmp = (uint2*)Hb;
  __hip_bfloat16* H2 = (__hip_bfloat16*)Abf;

  hipMemsetAsync(counts, 0, (size_t)NN * 4, stream);

  k_conv_a  <<<78125, 256, 0, stream>>>((const float4*)emb, (ushort4*)Abf);
  k_build_bt<<<4000,  256, 0, stream>>>(w1, Bt);
  k_hist    <<<12500, 256, 0, stream>>>(es, counts);
  k_part    <<<NBUSED, 256, 0, stream>>>(counts, part);
  k_scan2   <<<1,      64, 0, stream>>>(part, bbase, bptr, offs);
  k_offs    <<<NBUSED,1024, 0, stream>>>(counts, bbase, offs, ptr);
  k_bucket  <<<(EE + MEDG - 1) / MEDG, 256, 0, stream>>>(es, ep, eo, ev, bptr, tmp);
  dim3 sg(NBUSED, SBPB);
  k_scatter2<<<sg,    256, 0, stream>>>(tmp, offs, ptr, recs);
  dim3 gg(5, 391);
  k_gemm    <<<gg,    256, 0, stream>>>(Abf, Bt, Hb);
  k_agg1    <<<12500, 256, 0, stream>>>(recs, offs, Hb, b1, h1);
  k_h2      <<<103125,256, 0, stream>>>(h1, w2, H2);
  k_agg2    <<<12500, 256, 0, stream>>>(recs, offs, H2, b2, out);
}